// Round 7
// baseline (1579.451 us; speedup 1.0000x reference)
//
#include <hip/hip_runtime.h>
#include <stdint.h>

#define BB 64
#define TT 512
#define EE 256
#define NTAG 4
// dynamic LDS: 32768 weight dwords + hq[2][64] + sums[2][4] (+pad)
#define SMEM_BYTES (131072 + 512 + 64)

typedef _Float16 f16;
typedef _Float16 half8 __attribute__((ext_vector_type(8)));
typedef float floatx4 __attribute__((ext_vector_type(4)));

__device__ __forceinline__ int dot4i8(uint32_t a, uint32_t b, int c) {
#if __has_builtin(__builtin_amdgcn_sdot4)
  return __builtin_amdgcn_sdot4((int)a, (int)b, c, false);
#else
  int r;
  asm("v_dot4_i32_i8 %0, %1, %2, %3" : "=v"(r) : "v"(a), "v"(b), "v"(c));
  return r;
#endif
}

__device__ __forceinline__ float sigm(float x) {
  x = fminf(fmaxf(x, -30.f), 30.f);
  return 1.f / (1.f + __expf(-x));
}
__device__ __forceinline__ float tanh_f(float x) {
  x = fminf(fmaxf(x, -15.f), 15.f);
  float e = __expf(-2.f * x);
  return (1.f - e) / (1.f + e);
}

// ---------------- pack: w_ih -> f16 Bmat rows (PLAIN order, matches gemm/xg/rec);
// w_hh -> int4 biased nibbles, layout [dir][kc=32][row=1024] dwords, + per-row scale absmax/7.
// Nibble placement per dword kc (cols 8kc..8kc+7): cols 0..3 -> nibbles 0,2,4,6 (lo);
// cols 4..7 -> nibbles 1,3,5,7 (hi), so rec's (v & 0x0F0F0F0F)/(v>>4 & ..) yields
// contiguous col-quads matching int8-h dwords 2kc / 2kc+1.
__global__ void pack_kernel(const float* __restrict__ wihf, const float* __restrict__ wihb,
                            const float* __restrict__ whhf, const float* __restrict__ whhb,
                            f16* __restrict__ bmat, uint32_t* __restrict__ w4,
                            float* __restrict__ swhh) {
  int wv = (blockIdx.x * 256 + threadIdx.x) >> 6;  // global wave 0..2047 = (dir,row)
  int lane = threadIdx.x & 63;
  if (wv >= 2048) return;
  int dir = wv >> 10;
  int g = wv & 1023;
  const float* wih = dir ? wihb : wihf;
  floatx4 v = *(const floatx4*)(wih + (size_t)g * EE + lane * 4);
  f16* bp = bmat + (size_t)wv * EE + lane * 4;
  bp[0] = (f16)v[0]; bp[1] = (f16)v[1]; bp[2] = (f16)v[2]; bp[3] = (f16)v[3];

  const float* whh = dir ? whhb : whhf;
  floatx4 w = *(const floatx4*)(whh + (size_t)g * EE + lane * 4);
  float am = fmaxf(fmaxf(fabsf(w[0]), fabsf(w[1])), fmaxf(fabsf(w[2]), fabsf(w[3])));
#pragma unroll
  for (int d = 1; d < 64; d <<= 1) am = fmaxf(am, __shfl_xor(am, d));
  float s = am * (1.f / 7.f);
  float inv = am > 0.f ? 7.f / am : 0.f;
  int q0 = max(-7, min(7, (int)rintf(w[0] * inv)));
  int q1 = max(-7, min(7, (int)rintf(w[1] * inv)));
  int q2 = max(-7, min(7, (int)rintf(w[2] * inv)));
  int q3 = max(-7, min(7, (int)rintf(w[3] * inv)));
  uint32_t n0 = (uint32_t)(q0 + 8), n1 = (uint32_t)(q1 + 8);
  uint32_t n2 = (uint32_t)(q2 + 8), n3 = (uint32_t)(q3 + 8);
  // even lane (group cols 0..3): nibbles 0,2,4,6 ; odd lane (cols 4..7): nibbles 1,3,5,7
  uint32_t hw = (lane & 1) ? ((n0 << 4) | (n1 << 12) | (n2 << 20) | (n3 << 28))
                           : (n0 | (n1 << 8) | (n2 << 16) | (n3 << 24));
  uint32_t other = __shfl_xor(hw, 1);
  if (!(lane & 1)) w4[(size_t)dir * 32768 + (lane >> 1) * 1024 + g] = hw | other;
  if (lane == 0) swhh[dir * 1024 + g] = s;
}

// ---------------- GEMM: xg = embeds @ w_ih^T  (f16 MFMA, fused embedding gather)
__global__ __launch_bounds__(256) void gemm_kernel(
    const int* __restrict__ sentence, const float* __restrict__ embedding,
    const f16* __restrict__ bmat, f16* __restrict__ xgF, f16* __restrict__ xgB,
    int t0f, int t0b, int L, int Lsh) {
  __shared__ __attribute__((aligned(16))) f16 As[128][72];
  __shared__ __attribute__((aligned(16))) f16 Bs[128][72];
  int rt = blockIdx.x;
  int nt = blockIdx.y;  // 0..7
  int tid = threadIdx.x;
  int lane = tid & 63;
  int wv = tid >> 6;
  int BL = BB * L;
  int rbase = rt * 128;
  int half = (rbase >= BL) ? 1 : 0;
  int rloc0 = rbase - half * BL;
  int t0 = half ? t0b : t0f;

  floatx4 acc[4][4];
#pragma unroll
  for (int i = 0; i < 4; ++i)
#pragma unroll
    for (int j2 = 0; j2 < 4; ++j2) acc[i][j2] = (floatx4){0.f, 0.f, 0.f, 0.f};

  int ar = tid >> 1;
  int part = tid & 1;
  int rl = rloc0 + ar;
  int b_ = rl >> Lsh;
  int dt = rl & (L - 1);
  int t_ = t0 + dt;
  int sidx = sentence[b_ * TT + t_];
  const float* arow = embedding + (size_t)sidx * EE + part * 32;
  const f16* brow = bmat + ((size_t)(half * 1024 + nt * 128 + ar)) * EE + part * 32;
  int wm = (wv >> 1) * 64, wn = (wv & 1) * 64;

  for (int kk = 0; kk < 4; ++kk) {
    int k0 = kk * 64;
#pragma unroll
    for (int i = 0; i < 4; ++i) {
      floatx4 a0 = *(const floatx4*)(arow + k0 + i * 8);
      floatx4 a1 = *(const floatx4*)(arow + k0 + i * 8 + 4);
      union { f16 h[8]; uint4 u; } cv;
      cv.h[0] = (f16)a0[0]; cv.h[1] = (f16)a0[1]; cv.h[2] = (f16)a0[2]; cv.h[3] = (f16)a0[3];
      cv.h[4] = (f16)a1[0]; cv.h[5] = (f16)a1[1]; cv.h[6] = (f16)a1[2]; cv.h[7] = (f16)a1[3];
      *(uint4*)(&As[ar][part * 32 + i * 8]) = cv.u;
    }
#pragma unroll
    for (int i = 0; i < 4; ++i) {
      uint4 bv = *(const uint4*)(brow + k0 + i * 8);
      *(uint4*)(&Bs[ar][part * 32 + i * 8]) = bv;
    }
    __syncthreads();
#pragma unroll
    for (int kf = 0; kf < 2; ++kf) {
      int ko = kf * 32 + (lane >> 4) * 8;
      half8 af[4], bf[4];
#pragma unroll
      for (int mi = 0; mi < 4; ++mi)
        af[mi] = *(const half8*)(&As[wm + mi * 16 + (lane & 15)][ko]);
#pragma unroll
      for (int ni = 0; ni < 4; ++ni)
        bf[ni] = *(const half8*)(&Bs[wn + ni * 16 + (lane & 15)][ko]);
#pragma unroll
      for (int mi = 0; mi < 4; ++mi)
#pragma unroll
        for (int ni = 0; ni < 4; ++ni)
          acc[mi][ni] = __builtin_amdgcn_mfma_f32_16x16x32_f16(af[mi], bf[ni], acc[mi][ni], 0, 0, 0);
    }
    __syncthreads();
  }
  f16* out = half ? xgB : xgF;
#pragma unroll
  for (int mi = 0; mi < 4; ++mi) {
#pragma unroll
    for (int ni = 0; ni < 4; ++ni) {
      int rowl = wm + mi * 16 + (lane >> 4) * 4;
      int coll = nt * 128 + wn + ni * 16 + (lane & 15);
#pragma unroll
      for (int r = 0; r < 4; ++r) {
        out[(size_t)(rloc0 + rowl + r) * 1024 + coll] = (f16)acc[mi][ni][r];
      }
    }
  }
}

// ---------------- recurrence v7: weights int4 in LDS (128 KB, staged once per launch).
// 128 WGs = (b,dir), 256 threads, thread j owns all 4 gate rows of dim j.
// preact = x + bias + s/127 * (sdot4(biased_nibbles, h_i8) - 8*sum(h_i8)).
__global__ __launch_bounds__(256, 1) void rec_kernel(
    const int* __restrict__ length, const f16* __restrict__ xgF, const f16* __restrict__ xgB,
    const uint32_t* __restrict__ w4, const float* __restrict__ swhh,
    const float* __restrict__ b_f, const float* __restrict__ b_b,
    f16* __restrict__ hsF, f16* __restrict__ hsB,
    float* __restrict__ hstate, float* __restrict__ cstate,
    int t0f, int t0b, int L, int first) {
  extern __shared__ uint32_t lds[];
  uint32_t* wl = lds;                       // [32 kc][1024 rows] dwords = 128 KB
  uint32_t* hq = lds + 32768;               // [2][64] int8-packed h
  int* sums = (int*)(lds + 32768 + 128);    // [2][4] wave partials of sum(h_i8)

  int wid = blockIdx.x;
  int b = wid >> 1, dir = wid & 1;
  int j = threadIdx.x;  // h dim 0..255
  int wv = j >> 6, lane = j & 63;
  int len = length[b];

  // stage weights global -> LDS (once per launch; thread-stride = conflict-free)
  const uint32_t* wg = w4 + (size_t)dir * 32768;
#pragma unroll 4
  for (int i = 0; i < 128; ++i) wl[i * 256 + j] = wg[i * 256 + j];

  const float* sb = swhh + dir * 1024;
  float swI = sb[j] * (1.f / 127.f), swF = sb[256 + j] * (1.f / 127.f);
  float swG = sb[512 + j] * (1.f / 127.f), swO = sb[768 + j] * (1.f / 127.f);
  const float* bias = dir ? b_b : b_f;
  float biI = bias[j], biF = bias[256 + j], biG = bias[512 + j], biO = bias[768 + j];

  float h = 0.f, c = 0.f;
  if (!first) {
    h = hstate[(dir * BB + b) * 256 + j];
    c = cstate[(dir * BB + b) * 256 + j];
  }
  const f16* xg = dir ? xgB : xgF;
  f16* hs = dir ? hsB : hsF;

  // init: pack h -> hq[0], block-reduce sum -> sums[0]
  {
    int q = max(-127, min(127, (int)rintf(h * 127.f)));
    ((uint8_t*)hq)[j] = (uint8_t)q;
    int s = q;
#pragma unroll
    for (int d = 1; d < 64; d <<= 1) s += __shfl_xor(s, d);
    if (lane == 0) sums[wv] = s;
  }
  __syncthreads();

  int tlo = dir ? t0b : t0f;
  int thi = min(tlo + L, len);
  int nsteps = thi - tlo;
  int p = 0;
  int r0 = b * L + (dir ? (thi - 1 - tlo) : 0);
  int sgn = dir ? -1 : 1;
  float xI_c = 0.f, xF_c = 0.f, xG_c = 0.f, xO_c = 0.f;
  if (nsteps > 0) {
    const f16* xr = xg + ((size_t)r0 << 10);
    xI_c = (float)xr[j]; xF_c = (float)xr[256 + j];
    xG_c = (float)xr[512 + j]; xO_c = (float)xr[768 + j];
  }

  for (int ii = 0; ii < nsteps; ++ii) {
    float xI_n = xI_c, xF_n = xF_c, xG_n = xG_c, xO_n = xO_c;
    if (ii + 1 < nsteps) {
      const f16* xr = xg + ((size_t)(r0 + sgn * (ii + 1)) << 10);
      xI_n = (float)xr[j]; xF_n = (float)xr[256 + j];
      xG_n = (float)xr[512 + j]; xO_n = (float)xr[768 + j];
    }
    int corr = 8 * (sums[p * 4 + 0] + sums[p * 4 + 1] + sums[p * 4 + 2] + sums[p * 4 + 3]);
    const uint32_t* hp = hq + p * 64;
    int aI0 = 0, aI1 = 0, aF0 = 0, aF1 = 0, aG0 = 0, aG1 = 0, aO0 = 0, aO1 = 0;
#pragma unroll
    for (int kc = 0; kc < 32; ++kc) {
      uint32_t hx = hp[2 * kc], hy = hp[2 * kc + 1];  // uniform -> LDS broadcast
      uint32_t nI = wl[kc * 1024 + j];
      uint32_t nF = wl[kc * 1024 + 256 + j];
      uint32_t nG = wl[kc * 1024 + 512 + j];
      uint32_t nO = wl[kc * 1024 + 768 + j];
      aI0 = dot4i8(nI & 0x0F0F0F0Fu, hx, aI0);
      aI1 = dot4i8((nI >> 4) & 0x0F0F0F0Fu, hy, aI1);
      aF0 = dot4i8(nF & 0x0F0F0F0Fu, hx, aF0);
      aF1 = dot4i8((nF >> 4) & 0x0F0F0F0Fu, hy, aF1);
      aG0 = dot4i8(nG & 0x0F0F0F0Fu, hx, aG0);
      aG1 = dot4i8((nG >> 4) & 0x0F0F0F0Fu, hy, aG1);
      aO0 = dot4i8(nO & 0x0F0F0F0Fu, hx, aO0);
      aO1 = dot4i8((nO >> 4) & 0x0F0F0F0Fu, hy, aO1);
    }
    float pI = xI_c + biI + swI * (float)(aI0 + aI1 - corr);
    float pF = xF_c + biF + swF * (float)(aF0 + aF1 - corr);
    float pG = xG_c + biG + swG * (float)(aG0 + aG1 - corr);
    float pO = xO_c + biO + swO * (float)(aO0 + aO1 - corr);
    float iv = sigm(pI), fv = sigm(pF), gv = tanh_f(pG), ov = sigm(pO);
    c = fv * c + iv * gv;
    h = ov * tanh_f(c);
    int t = dir ? (thi - 1 - ii) : (tlo + ii);
    hs[(((size_t)(b * TT + t)) << 8) + j] = (f16)h;  // fire-and-forget
    int qn = max(-127, min(127, (int)rintf(h * 127.f)));
    ((uint8_t*)(hq + (p ^ 1) * 64))[j] = (uint8_t)qn;
    int s2 = qn;
#pragma unroll
    for (int d = 1; d < 64; d <<= 1) s2 += __shfl_xor(s2, d);
    if (lane == 0) sums[(p ^ 1) * 4 + wv] = s2;
    __syncthreads();
    p ^= 1;
    xI_c = xI_n; xF_c = xF_n; xG_c = xG_n; xO_c = xO_n;
  }
  hstate[(dir * BB + b) * 256 + j] = h;
  cstate[(dir * BB + b) * 256 + j] = c;
}

// ---------------- feats: [hf|hb] @ w_out^T + b_out, one wave per row
__global__ __launch_bounds__(256) void feats_kernel(
    const f16* __restrict__ hsF, const f16* __restrict__ hsB,
    const float* __restrict__ w_out, const float* __restrict__ b_out,
    float* __restrict__ feats) {
  int gw = (blockIdx.x * 256 + threadIdx.x) >> 6;
  int lane = threadIdx.x & 63;
  int nw = (gridDim.x * 256) >> 6;
  float w0[8], w1[8], w2[8], w3[8];
#pragma unroll
  for (int u = 0; u < 8; ++u) {
    w0[u] = w_out[0 * 512 + lane * 8 + u];
    w1[u] = w_out[1 * 512 + lane * 8 + u];
    w2[u] = w_out[2 * 512 + lane * 8 + u];
    w3[u] = w_out[3 * 512 + lane * 8 + u];
  }
  float bo0 = b_out[0], bo1 = b_out[1], bo2 = b_out[2], bo3 = b_out[3];
  const f16* src0 = (lane < 32) ? (hsF + lane * 8) : (hsB + (lane - 32) * 8);
  for (int row = gw; row < BB * TT; row += nw) {
    union { uint4 u; f16 h[8]; } hv;
    hv.u = *(const uint4*)(src0 + ((size_t)row << 8));
    float a0 = 0.f, a1 = 0.f, a2 = 0.f, a3 = 0.f;
#pragma unroll
    for (int u2 = 0; u2 < 8; ++u2) {
      float x = (float)hv.h[u2];
      a0 += x * w0[u2]; a1 += x * w1[u2]; a2 += x * w2[u2]; a3 += x * w3[u2];
    }
#pragma unroll
    for (int d = 1; d < 64; d <<= 1) {
      a0 += __shfl_xor(a0, d); a1 += __shfl_xor(a1, d);
      a2 += __shfl_xor(a2, d); a3 += __shfl_xor(a3, d);
    }
    if (lane == 0) {
      floatx4 o = {a0 + bo0, a1 + bo1, a2 + bo2, a3 + bo3};
      *(floatx4*)(feats + (size_t)row * 4) = o;
    }
  }
}

// ---------------- CRF: numerator + forward algorithm, one wave per batch
__global__ void crf_kernel(const int* __restrict__ tags, const int* __restrict__ length,
                           const float* __restrict__ feats,
                           const float* __restrict__ start_trans,
                           const float* __restrict__ end_trans, const float* __restrict__ trans,
                           float* __restrict__ res) {
  int b = blockIdx.x;
  int lane = threadIdx.x;
  int len = length[b];
  float tr0 = lane < 4 ? trans[0 * 4 + lane] : 0.f;
  float tr1 = lane < 4 ? trans[1 * 4 + lane] : 0.f;
  float tr2 = lane < 4 ? trans[2 * 4 + lane] : 0.f;
  float tr3 = lane < 4 ? trans[3 * 4 + lane] : 0.f;
  float treg = lane < 16 ? trans[lane] : 0.f;
  float st = lane < 4 ? start_trans[lane] : 0.f;
  float en = lane < 4 ? end_trans[lane] : 0.f;
  const int* tg = tags + b * TT;
  const float* fb = feats + (size_t)b * TT * 4;

  float e = lane < 4 ? fb[lane] : 0.f;
  int prev = tg[0];
  float alpha = st + e;
  float num = __shfl(st + e, prev);
#pragma unroll 2
  for (int t = 1; t < len; ++t) {
    float et = lane < 4 ? fb[t * 4 + lane] : 0.f;
    int cur = tg[t];
    float a0 = __shfl(alpha, 0), a1 = __shfl(alpha, 1), a2 = __shfl(alpha, 2), a3 = __shfl(alpha, 3);
    float v0 = a0 + tr0, v1 = a1 + tr1, v2 = a2 + tr2, v3 = a3 + tr3;
    float mx = fmaxf(fmaxf(v0, v1), fmaxf(v2, v3));
    float sm = __expf(v0 - mx) + __expf(v1 - mx) + __expf(v2 - mx) + __expf(v3 - mx);
    alpha = mx + __logf(sm) + et;
    num += __shfl(et, cur) + __shfl(treg, prev * 4 + cur);
    prev = cur;
  }
  num += __shfl(en, prev);
  float v = alpha + en;
  float z0 = __shfl(v, 0), z1 = __shfl(v, 1), z2 = __shfl(v, 2), z3 = __shfl(v, 3);
  float mx = fmaxf(fmaxf(z0, z1), fmaxf(z2, z3));
  float logZ = mx + __logf(__expf(z0 - mx) + __expf(z1 - mx) + __expf(z2 - mx) + __expf(z3 - mx));
  if (lane == 0) res[b] = num - logZ;
}

__global__ void loss_kernel(const float* __restrict__ res, float* __restrict__ out) {
  int lane = threadIdx.x;
  float v = res[lane];
#pragma unroll
  for (int d = 1; d < 64; d <<= 1) v += __shfl_xor(v, d);
  if (lane == 0) out[0] = -v * (1.f / 64.f);
}

extern "C" void kernel_launch(void* const* d_in, const int* in_sizes, int n_in,
                              void* d_out, int out_size, void* d_ws, size_t ws_size,
                              hipStream_t stream) {
  (void)in_sizes; (void)n_in; (void)out_size;
  const int* sentence = (const int*)d_in[0];
  const int* tags = (const int*)d_in[1];
  const int* length = (const int*)d_in[3];
  const float* embedding = (const float*)d_in[4];
  const float* w_ih_f = (const float*)d_in[5];
  const float* w_hh_f = (const float*)d_in[6];
  const float* b_f = (const float*)d_in[7];
  const float* w_ih_b = (const float*)d_in[8];
  const float* w_hh_b = (const float*)d_in[9];
  const float* b_b = (const float*)d_in[10];
  const float* w_out = (const float*)d_in[11];
  const float* b_out = (const float*)d_in[12];
  const float* start_trans = (const float*)d_in[13];
  const float* end_trans = (const float*)d_in[14];
  const float* trans = (const float*)d_in[15];

  // allow >64KB dynamic LDS for rec_kernel (idempotent, host-side, capture-safe)
  static_assert(SMEM_BYTES <= 160 * 1024, "LDS overflow");
  (void)hipFuncSetAttribute(reinterpret_cast<const void*>(rec_kernel),
                            hipFuncAttributeMaxDynamicSharedMemorySize, SMEM_BYTES);

  char* ws = (char*)d_ws;
  size_t off = 0;
  auto take = [&](size_t bytes) -> char* {
    char* p = ws + off;
    off = (off + bytes + 255) & ~(size_t)255;
    return p;
  };
  f16* bmat = (f16*)take((size_t)2048 * 256 * 2);
  uint32_t* w4 = (uint32_t*)take((size_t)2 * 32768 * 4);
  float* swhh = (float*)take((size_t)2 * 1024 * 4);
  f16* hsF = (f16*)take((size_t)BB * TT * 256 * 2);
  f16* hsB = (f16*)take((size_t)BB * TT * 256 * 2);
  float* feats = (float*)take((size_t)BB * TT * NTAG * 4);
  float* hstate = (float*)take((size_t)2 * BB * 256 * 4);
  float* cstate = (float*)take((size_t)2 * BB * 256 * 4);
  float* res = (float*)take(256);
  size_t fixed = off;

  int L = TT, Lsh = 9;
  while (L > 32 && fixed + (size_t)BB * L * 1024 * 2 * 2 > ws_size) { L >>= 1; Lsh--; }
  f16* xgF = (f16*)take((size_t)BB * L * 1024 * 2);
  f16* xgB = (f16*)take((size_t)BB * L * 1024 * 2);
  int NC = TT / L;

  hipLaunchKernelGGL(pack_kernel, dim3(512), dim3(256), 0, stream,
                     w_ih_f, w_ih_b, w_hh_f, w_hh_b, bmat, w4, swhh);

  for (int cidx = 0; cidx < NC; ++cidx) {
    int t0f_ = cidx * L;
    int t0b_ = TT - (cidx + 1) * L;
    hipLaunchKernelGGL(gemm_kernel, dim3(2 * BB * L / 128, 8), dim3(256), 0, stream,
                       sentence, embedding, bmat, xgF, xgB, t0f_, t0b_, L, Lsh);
    hipLaunchKernelGGL(rec_kernel, dim3(128), dim3(256), SMEM_BYTES, stream,
                       length, xgF, xgB, w4, swhh, b_f, b_b, hsF, hsB,
                       hstate, cstate, t0f_, t0b_, L, cidx == 0 ? 1 : 0);
  }
  hipLaunchKernelGGL(feats_kernel, dim3(512), dim3(256), 0, stream,
                     hsF, hsB, w_out, b_out, feats);
  hipLaunchKernelGGL(crf_kernel, dim3(BB), dim3(64), 0, stream,
                     tags, length, feats, start_trans, end_trans, trans, res);
  hipLaunchKernelGGL(loss_kernel, dim3(1), dim3(64), 0, stream, res, (float*)d_out);
}

// Round 9
// 1056.760 us; speedup vs baseline: 1.4946x; 1.4946x over previous
//
#include <hip/hip_runtime.h>
#include <stdint.h>

#define BB 64
#define TT 512
#define EE 256
#define NTAG 4

typedef _Float16 f16;
typedef _Float16 half8 __attribute__((ext_vector_type(8)));
typedef float floatx4 __attribute__((ext_vector_type(4)));

__device__ __forceinline__ int dot4i8(uint32_t a, uint32_t b, int c) {
#if __has_builtin(__builtin_amdgcn_sdot4)
  return __builtin_amdgcn_sdot4((int)a, (int)b, c, false);
#else
  int r;
  asm("v_dot4_i32_i8 %0, %1, %2, %3" : "=v"(r) : "v"(a), "v"(b), "v"(c));
  return r;
#endif
}

__device__ __forceinline__ float sigm(float x) {
  x = fminf(fmaxf(x, -30.f), 30.f);
  return 1.f / (1.f + __expf(-x));
}
__device__ __forceinline__ float tanh_f(float x) {
  x = fminf(fmaxf(x, -15.f), 15.f);
  float e = __expf(-2.f * x);
  return (1.f - e) / (1.f + e);
}

// ---------------- pack: w_ih -> f16 Bmat rows (plain row order);
//                   w_hh -> i8, layout [dir][kc=64][row=1024], + per-row scales
__global__ void pack_kernel(const float* __restrict__ wihf, const float* __restrict__ wihb,
                            const float* __restrict__ whhf, const float* __restrict__ whhb,
                            f16* __restrict__ bmat, uint32_t* __restrict__ whhp,
                            float* __restrict__ swhh) {
  int wv = (blockIdx.x * 256 + threadIdx.x) >> 6;  // global wave 0..2047 = (dir,row)
  int lane = threadIdx.x & 63;
  if (wv >= 2048) return;
  int dir = wv >> 10;
  int g = wv & 1023;
  const float* wih = dir ? wihb : wihf;
  floatx4 v = *(const floatx4*)(wih + (size_t)g * EE + lane * 4);
  f16* bp = bmat + (size_t)wv * EE + lane * 4;
  bp[0] = (f16)v[0]; bp[1] = (f16)v[1]; bp[2] = (f16)v[2]; bp[3] = (f16)v[3];

  const float* whh = dir ? whhb : whhf;
  floatx4 w = *(const floatx4*)(whh + (size_t)g * EE + lane * 4);
  float am = fmaxf(fmaxf(fabsf(w[0]), fabsf(w[1])), fmaxf(fabsf(w[2]), fabsf(w[3])));
#pragma unroll
  for (int d = 1; d < 64; d <<= 1) am = fmaxf(am, __shfl_xor(am, d));
  float s = am * (1.f / 127.f);
  float inv = am > 0.f ? 127.f / am : 0.f;
  int q0 = (int)rintf(w[0] * inv);
  int q1 = (int)rintf(w[1] * inv);
  int q2 = (int)rintf(w[2] * inv);
  int q3 = (int)rintf(w[3] * inv);
  uint32_t p = (uint32_t)(q0 & 255) | ((uint32_t)(q1 & 255) << 8) |
               ((uint32_t)(q2 & 255) << 16) | ((uint32_t)(q3 & 255) << 24);
  whhp[dir * 65536 + lane * 1024 + g] = p;  // [dir][kc=lane][row=g]
  if (lane == 0) swhh[dir * 1024 + g] = s;
}

// ---------------- GEMM: xg = embeds @ w_ih^T  (f16 MFMA, fused embedding gather)
__global__ __launch_bounds__(256) void gemm_kernel(
    const int* __restrict__ sentence, const float* __restrict__ embedding,
    const f16* __restrict__ bmat, f16* __restrict__ xgF, f16* __restrict__ xgB,
    int t0f, int t0b, int L, int Lsh) {
  __shared__ __attribute__((aligned(16))) f16 As[128][72];
  __shared__ __attribute__((aligned(16))) f16 Bs[128][72];
  int rt = blockIdx.x;
  int nt = blockIdx.y;  // 0..7
  int tid = threadIdx.x;
  int lane = tid & 63;
  int wv = tid >> 6;
  int BL = BB * L;
  int rbase = rt * 128;
  int half = (rbase >= BL) ? 1 : 0;
  int rloc0 = rbase - half * BL;
  int t0 = half ? t0b : t0f;

  floatx4 acc[4][4];
#pragma unroll
  for (int i = 0; i < 4; ++i)
#pragma unroll
    for (int j2 = 0; j2 < 4; ++j2) acc[i][j2] = (floatx4){0.f, 0.f, 0.f, 0.f};

  int ar = tid >> 1;
  int part = tid & 1;
  int rl = rloc0 + ar;
  int b_ = rl >> Lsh;
  int dt = rl & (L - 1);
  int t_ = t0 + dt;
  int sidx = sentence[b_ * TT + t_];
  const float* arow = embedding + (size_t)sidx * EE + part * 32;
  const f16* brow = bmat + ((size_t)(half * 1024 + nt * 128 + ar)) * EE + part * 32;
  int wm = (wv >> 1) * 64, wn = (wv & 1) * 64;

  for (int kk = 0; kk < 4; ++kk) {
    int k0 = kk * 64;
#pragma unroll
    for (int i = 0; i < 4; ++i) {
      floatx4 a0 = *(const floatx4*)(arow + k0 + i * 8);
      floatx4 a1 = *(const floatx4*)(arow + k0 + i * 8 + 4);
      union { f16 h[8]; uint4 u; } cv;
      cv.h[0] = (f16)a0[0]; cv.h[1] = (f16)a0[1]; cv.h[2] = (f16)a0[2]; cv.h[3] = (f16)a0[3];
      cv.h[4] = (f16)a1[0]; cv.h[5] = (f16)a1[1]; cv.h[6] = (f16)a1[2]; cv.h[7] = (f16)a1[3];
      *(uint4*)(&As[ar][part * 32 + i * 8]) = cv.u;
    }
#pragma unroll
    for (int i = 0; i < 4; ++i) {
      uint4 bv = *(const uint4*)(brow + k0 + i * 8);
      *(uint4*)(&Bs[ar][part * 32 + i * 8]) = bv;
    }
    __syncthreads();
#pragma unroll
    for (int kf = 0; kf < 2; ++kf) {
      int ko = kf * 32 + (lane >> 4) * 8;
      half8 af[4], bf[4];
#pragma unroll
      for (int mi = 0; mi < 4; ++mi)
        af[mi] = *(const half8*)(&As[wm + mi * 16 + (lane & 15)][ko]);
#pragma unroll
      for (int ni = 0; ni < 4; ++ni)
        bf[ni] = *(const half8*)(&Bs[wn + ni * 16 + (lane & 15)][ko]);
#pragma unroll
      for (int mi = 0; mi < 4; ++mi)
#pragma unroll
        for (int ni = 0; ni < 4; ++ni)
          acc[mi][ni] = __builtin_amdgcn_mfma_f32_16x16x32_f16(af[mi], bf[ni], acc[mi][ni], 0, 0, 0);
    }
    __syncthreads();
  }
  f16* out = half ? xgB : xgF;
#pragma unroll
  for (int mi = 0; mi < 4; ++mi) {
#pragma unroll
    for (int ni = 0; ni < 4; ++ni) {
      int rowl = wm + mi * 16 + (lane >> 4) * 4;
      int coll = nt * 128 + wn + ni * 16 + (lane & 15);
#pragma unroll
      for (int r = 0; r < 4; ++r) {
        out[(size_t)(rloc0 + rowl + r) * 1024 + coll] = (f16)acc[mi][ni][r];
      }
    }
  }
}

// ---------------- recurrence v8b: 128 WGs = (b,dir), 1024 threads, 1 gate-row/thread.
// 64 int8 weight dwords/thread in VGPRs (16 waves -> 4 waves/SIMD hides latency).
// h broadcast: each wave holds packed-i8 h in its 64 lanes; dot via readlane->SGPR sdot4.
#define L16A(M) M(0) M(1) M(2) M(3) M(4) M(5) M(6) M(7) \
                M(8) M(9) M(10) M(11) M(12) M(13) M(14) M(15)
#define L16B(M) M(16) M(17) M(18) M(19) M(20) M(21) M(22) M(23) \
                M(24) M(25) M(26) M(27) M(28) M(29) M(30) M(31)
#define L16C(M) M(32) M(33) M(34) M(35) M(36) M(37) M(38) M(39) \
                M(40) M(41) M(42) M(43) M(44) M(45) M(46) M(47)
#define L16D(M) M(48) M(49) M(50) M(51) M(52) M(53) M(54) M(55) \
                M(56) M(57) M(58) M(59) M(60) M(61) M(62) M(63)

#define LW(k) uint32_t W##k = wp[(k)*1024 + row];

#define DG(k0, k1, k2, k3) \
  a0 = dot4i8(W##k0, (uint32_t)__builtin_amdgcn_readlane((int)hreg, k0), a0); \
  a1 = dot4i8(W##k1, (uint32_t)__builtin_amdgcn_readlane((int)hreg, k1), a1); \
  a2 = dot4i8(W##k2, (uint32_t)__builtin_amdgcn_readlane((int)hreg, k2), a2); \
  a3 = dot4i8(W##k3, (uint32_t)__builtin_amdgcn_readlane((int)hreg, k3), a3);

__global__ __launch_bounds__(1024, 1) void rec_kernel(
    const int* __restrict__ length, const f16* __restrict__ xgF, const f16* __restrict__ xgB,
    const uint32_t* __restrict__ whhp, const float* __restrict__ swhh,
    const float* __restrict__ b_f, const float* __restrict__ b_b,
    f16* __restrict__ hsF, f16* __restrict__ hsB,
    float* __restrict__ hstate, float* __restrict__ cstate,
    int t0f, int t0b, int L, int first) {
  __shared__ float gacts[1024];
  __shared__ __attribute__((aligned(16))) uint32_t hq[64];

  int wid = blockIdx.x;
  int b = wid >> 1, dir = wid & 1;
  int tid = threadIdx.x;   // = row = gate*256 + dim
  int row = tid;
  int gate = tid >> 8;     // wave-uniform (waves 0-3:i, 4-7:f, 8-11:g, 12-15:o)
  int lane = tid & 63;
  int len = length[b];

  const uint32_t* wp = whhp + dir * 65536;
  // 64 named weight dwords -> VGPRs
  L16A(LW) L16B(LW) L16C(LW) L16D(LW)
  // opaque pin (blocks remat-by-reload; no-op instruction-wise)
  asm volatile("" : "+v"(W0), "+v"(W1), "+v"(W2), "+v"(W3), "+v"(W4), "+v"(W5), "+v"(W6),
                    "+v"(W7), "+v"(W8), "+v"(W9), "+v"(W10), "+v"(W11), "+v"(W12), "+v"(W13),
                    "+v"(W14), "+v"(W15));
  asm volatile("" : "+v"(W16), "+v"(W17), "+v"(W18), "+v"(W19), "+v"(W20), "+v"(W21),
                    "+v"(W22), "+v"(W23), "+v"(W24), "+v"(W25), "+v"(W26), "+v"(W27),
                    "+v"(W28), "+v"(W29), "+v"(W30), "+v"(W31));
  asm volatile("" : "+v"(W32), "+v"(W33), "+v"(W34), "+v"(W35), "+v"(W36), "+v"(W37),
                    "+v"(W38), "+v"(W39), "+v"(W40), "+v"(W41), "+v"(W42), "+v"(W43),
                    "+v"(W44), "+v"(W45), "+v"(W46), "+v"(W47));
  asm volatile("" : "+v"(W48), "+v"(W49), "+v"(W50), "+v"(W51), "+v"(W52), "+v"(W53),
                    "+v"(W54), "+v"(W55), "+v"(W56), "+v"(W57), "+v"(W58), "+v"(W59),
                    "+v"(W60), "+v"(W61), "+v"(W62), "+v"(W63));

  float sw = swhh[dir * 1024 + row] * (1.f / 127.f);
  const float* bias = dir ? b_b : b_f;
  float bi = bias[row];

  float h = 0.f, c = 0.f;
  if (!first && tid < 256) {
    h = hstate[(dir * BB + b) * 256 + tid];
    c = cstate[(dir * BB + b) * 256 + tid];
  }
  const f16* xg = dir ? xgB : xgF;
  f16* hs = dir ? hsB : hsF;

  // init: pack h (threads 0..255) -> hq, then all waves pick it up into lanes
  if (tid < 256) {
    int q = max(-127, min(127, (int)rintf(h * 127.f)));
    ((uint8_t*)hq)[tid] = (uint8_t)q;
  }
  __syncthreads();
  uint32_t hreg = hq[lane];

  int tlo = dir ? t0b : t0f;
  int thi = min(tlo + L, len);
  int nsteps = thi - tlo;
  int r0 = b * L + (dir ? (thi - 1 - tlo) : 0);
  int sgn = dir ? -1 : 1;
  float xv_c = 0.f;
  if (nsteps > 0) xv_c = (float)xg[(((size_t)r0) << 10) + row];

  for (int ii = 0; ii < nsteps; ++ii) {
    float xv_n = xv_c;
    if (ii + 1 < nsteps)
      xv_n = (float)xg[(((size_t)(r0 + sgn * (ii + 1))) << 10) + row];
    int a0 = 0, a1 = 0, a2 = 0, a3 = 0;
    DG(0, 1, 2, 3)     DG(4, 5, 6, 7)     DG(8, 9, 10, 11)   DG(12, 13, 14, 15)
    DG(16, 17, 18, 19) DG(20, 21, 22, 23) DG(24, 25, 26, 27) DG(28, 29, 30, 31)
    DG(32, 33, 34, 35) DG(36, 37, 38, 39) DG(40, 41, 42, 43) DG(44, 45, 46, 47)
    DG(48, 49, 50, 51) DG(52, 53, 54, 55) DG(56, 57, 58, 59) DG(60, 61, 62, 63)
    float pre = xv_c + bi + sw * (float)((a0 + a1) + (a2 + a3));
    gacts[row] = (gate == 2) ? tanh_f(pre) : sigm(pre);
    __syncthreads();  // B1: gates ready
    if (tid < 256) {
      float iv = gacts[tid], fv = gacts[256 + tid], gv = gacts[512 + tid], ov = gacts[768 + tid];
      c = fv * c + iv * gv;
      h = ov * tanh_f(c);
      int t = dir ? (thi - 1 - ii) : (tlo + ii);
      hs[(((size_t)(b * TT + t)) << 8) + tid] = (f16)h;  // fire-and-forget
      int q = max(-127, min(127, (int)rintf(h * 127.f)));
      ((uint8_t*)hq)[tid] = (uint8_t)q;
    }
    __syncthreads();  // B2: new h published
    hreg = hq[lane];
    xv_c = xv_n;
  }
  if (tid < 256) {
    hstate[(dir * BB + b) * 256 + tid] = h;
    cstate[(dir * BB + b) * 256 + tid] = c;
  }
}

// ---------------- feats: [hf|hb] @ w_out^T + b_out, one wave per row
__global__ __launch_bounds__(256) void feats_kernel(
    const f16* __restrict__ hsF, const f16* __restrict__ hsB,
    const float* __restrict__ w_out, const float* __restrict__ b_out,
    float* __restrict__ feats) {
  int gw = (blockIdx.x * 256 + threadIdx.x) >> 6;
  int lane = threadIdx.x & 63;
  int nw = (gridDim.x * 256) >> 6;
  float w0[8], w1[8], w2[8], w3[8];
#pragma unroll
  for (int u = 0; u < 8; ++u) {
    w0[u] = w_out[0 * 512 + lane * 8 + u];
    w1[u] = w_out[1 * 512 + lane * 8 + u];
    w2[u] = w_out[2 * 512 + lane * 8 + u];
    w3[u] = w_out[3 * 512 + lane * 8 + u];
  }
  float bo0 = b_out[0], bo1 = b_out[1], bo2 = b_out[2], bo3 = b_out[3];
  const f16* src0 = (lane < 32) ? (hsF + lane * 8) : (hsB + (lane - 32) * 8);
  for (int row = gw; row < BB * TT; row += nw) {
    union { uint4 u; f16 h[8]; } hv;
    hv.u = *(const uint4*)(src0 + ((size_t)row << 8));
    float a0 = 0.f, a1 = 0.f, a2 = 0.f, a3 = 0.f;
#pragma unroll
    for (int u2 = 0; u2 < 8; ++u2) {
      float x = (float)hv.h[u2];
      a0 += x * w0[u2]; a1 += x * w1[u2]; a2 += x * w2[u2]; a3 += x * w3[u2];
    }
#pragma unroll
    for (int d = 1; d < 64; d <<= 1) {
      a0 += __shfl_xor(a0, d); a1 += __shfl_xor(a1, d);
      a2 += __shfl_xor(a2, d); a3 += __shfl_xor(a3, d);
    }
    if (lane == 0) {
      floatx4 o = {a0 + bo0, a1 + bo1, a2 + bo2, a3 + bo3};
      *(floatx4*)(feats + (size_t)row * 4) = o;
    }
  }
}

// ---------------- CRF: numerator + forward algorithm, one wave per batch
__global__ void crf_kernel(const int* __restrict__ tags, const int* __restrict__ length,
                           const float* __restrict__ feats,
                           const float* __restrict__ start_trans,
                           const float* __restrict__ end_trans, const float* __restrict__ trans,
                           float* __restrict__ res) {
  int b = blockIdx.x;
  int lane = threadIdx.x;
  int len = length[b];
  float tr0 = lane < 4 ? trans[0 * 4 + lane] : 0.f;
  float tr1 = lane < 4 ? trans[1 * 4 + lane] : 0.f;
  float tr2 = lane < 4 ? trans[2 * 4 + lane] : 0.f;
  float tr3 = lane < 4 ? trans[3 * 4 + lane] : 0.f;
  float treg = lane < 16 ? trans[lane] : 0.f;
  float st = lane < 4 ? start_trans[lane] : 0.f;
  float en = lane < 4 ? end_trans[lane] : 0.f;
  const int* tg = tags + b * TT;
  const float* fb = feats + (size_t)b * TT * 4;

  float e = lane < 4 ? fb[lane] : 0.f;
  int prev = tg[0];
  float alpha = st + e;
  float num = __shfl(st + e, prev);
#pragma unroll 2
  for (int t = 1; t < len; ++t) {
    float et = lane < 4 ? fb[t * 4 + lane] : 0.f;
    int cur = tg[t];
    float a0 = __shfl(alpha, 0), a1 = __shfl(alpha, 1), a2 = __shfl(alpha, 2), a3 = __shfl(alpha, 3);
    float v0 = a0 + tr0, v1 = a1 + tr1, v2 = a2 + tr2, v3 = a3 + tr3;
    float mx = fmaxf(fmaxf(v0, v1), fmaxf(v2, v3));
    float sm = __expf(v0 - mx) + __expf(v1 - mx) + __expf(v2 - mx) + __expf(v3 - mx);
    alpha = mx + __logf(sm) + et;
    num += __shfl(et, cur) + __shfl(treg, prev * 4 + cur);
    prev = cur;
  }
  num += __shfl(en, prev);
  float v = alpha + en;
  float z0 = __shfl(v, 0), z1 = __shfl(v, 1), z2 = __shfl(v, 2), z3 = __shfl(v, 3);
  float mx = fmaxf(fmaxf(z0, z1), fmaxf(z2, z3));
  float logZ = mx + __logf(__expf(z0 - mx) + __expf(z1 - mx) + __expf(z2 - mx) + __expf(z3 - mx));
  if (lane == 0) res[b] = num - logZ;
}

__global__ void loss_kernel(const float* __restrict__ res, float* __restrict__ out) {
  int lane = threadIdx.x;
  float v = res[lane];
#pragma unroll
  for (int d = 1; d < 64; d <<= 1) v += __shfl_xor(v, d);
  if (lane == 0) out[0] = -v * (1.f / 64.f);
}

extern "C" void kernel_launch(void* const* d_in, const int* in_sizes, int n_in,
                              void* d_out, int out_size, void* d_ws, size_t ws_size,
                              hipStream_t stream) {
  (void)in_sizes; (void)n_in; (void)out_size;
  const int* sentence = (const int*)d_in[0];
  const int* tags = (const int*)d_in[1];
  const int* length = (const int*)d_in[3];
  const float* embedding = (const float*)d_in[4];
  const float* w_ih_f = (const float*)d_in[5];
  const float* w_hh_f = (const float*)d_in[6];
  const float* b_f = (const float*)d_in[7];
  const float* w_ih_b = (const float*)d_in[8];
  const float* w_hh_b = (const float*)d_in[9];
  const float* b_b = (const float*)d_in[10];
  const float* w_out = (const float*)d_in[11];
  const float* b_out = (const float*)d_in[12];
  const float* start_trans = (const float*)d_in[13];
  const float* end_trans = (const float*)d_in[14];
  const float* trans = (const float*)d_in[15];

  char* ws = (char*)d_ws;
  size_t off = 0;
  auto take = [&](size_t bytes) -> char* {
    char* p = ws + off;
    off = (off + bytes + 255) & ~(size_t)255;
    return p;
  };
  f16* bmat = (f16*)take((size_t)2048 * 256 * 2);
  uint32_t* whhp = (uint32_t*)take((size_t)2 * 64 * 1024 * 4);
  float* swhh = (float*)take((size_t)2 * 1024 * 4);
  f16* hsF = (f16*)take((size_t)BB * TT * 256 * 2);
  f16* hsB = (f16*)take((size_t)BB * TT * 256 * 2);
  float* feats = (float*)take((size_t)BB * TT * NTAG * 4);
  float* hstate = (float*)take((size_t)2 * BB * 256 * 4);
  float* cstate = (float*)take((size_t)2 * BB * 256 * 4);
  float* res = (float*)take(256);
  size_t fixed = off;

  int L = TT, Lsh = 9;
  while (L > 32 && fixed + (size_t)BB * L * 1024 * 2 * 2 > ws_size) { L >>= 1; Lsh--; }
  f16* xgF = (f16*)take((size_t)BB * L * 1024 * 2);
  f16* xgB = (f16*)take((size_t)BB * L * 1024 * 2);
  int NC = TT / L;

  hipLaunchKernelGGL(pack_kernel, dim3(512), dim3(256), 0, stream,
                     w_ih_f, w_ih_b, w_hh_f, w_hh_b, bmat, whhp, swhh);

  for (int cidx = 0; cidx < NC; ++cidx) {
    int t0f_ = cidx * L;
    int t0b_ = TT - (cidx + 1) * L;
    hipLaunchKernelGGL(gemm_kernel, dim3(2 * BB * L / 128, 8), dim3(256), 0, stream,
                       sentence, embedding, bmat, xgF, xgB, t0f_, t0b_, L, Lsh);
    hipLaunchKernelGGL(rec_kernel, dim3(128), dim3(1024), 0, stream,
                       length, xgF, xgB, whhp, swhh, b_f, b_b, hsF, hsB,
                       hstate, cstate, t0f_, t0b_, L, cidx == 0 ? 1 : 0);
  }
  hipLaunchKernelGGL(feats_kernel, dim3(512), dim3(256), 0, stream,
                     hsF, hsB, w_out, b_out, feats);
  hipLaunchKernelGGL(crf_kernel, dim3(BB), dim3(64), 0, stream,
                     tags, length, feats, start_trans, end_trans, trans, res);
  hipLaunchKernelGGL(loss_kernel, dim3(1), dim3(64), 0, stream, res, (float*)d_out);
}